// Round 6
// baseline (728.171 us; speedup 1.0000x reference)
//
#include <hip/hip_runtime.h>

#define HID 256
#define EPSV 1e-5f
#define ASTR 72   // layer-0 At row stride (ushorts): 64 data + 8 pad
#define BSTR 40   // 32 data + 8 pad

typedef __bf16 bf16x8 __attribute__((ext_vector_type(8)));
typedef float  floatx4 __attribute__((ext_vector_type(4)));

static __device__ __forceinline__ ushort f2bf(float f) {
  union { float f; unsigned int i; } c; c.f = f;
  unsigned int u = c.i;
  u += 0x7FFFu + ((u >> 16) & 1u);   // round-to-nearest-even
  return (ushort)(u >> 16);
}
static __device__ __forceinline__ float bf2f(ushort u) {
  union { unsigned int i; float f; } c; c.i = ((unsigned int)u) << 16; return c.f;
}

// ---------------- CSR build ----------------
__global__ void count_kernel(const int* __restrict__ ei, int* __restrict__ deg, int E, int tot) {
  int i = blockIdx.x * blockDim.x + threadIdx.x;
  if (i < tot) {
    int dst = (i < E) ? ei[E + i] : (i - E);
    atomicAdd(&deg[dst], 1);
  }
}

// hierarchical exclusive scan of deg -> rp
__global__ void scanA_kernel(const int* __restrict__ deg, int* __restrict__ incl,
                             int* __restrict__ sums, int n) {
  __shared__ int buf[1024];
  const int t = threadIdx.x;
  const int i = blockIdx.x * 1024 + t;
  int x = (i < n) ? deg[i] : 0;
  buf[t] = x;
  __syncthreads();
  for (int off = 1; off < 1024; off <<= 1) {
    int v = (t >= off) ? buf[t - off] : 0;
    __syncthreads();
    buf[t] += v;
    __syncthreads();
  }
  if (i < n) incl[i] = buf[t];
  if (t == 1023) sums[blockIdx.x] = buf[1023];
}

__global__ void scanB_kernel(int* __restrict__ sums, int* __restrict__ offs, int nblk) {
  __shared__ int buf[256];
  const int t = threadIdx.x;
  int x = (t < nblk) ? sums[t] : 0;
  buf[t] = x;
  __syncthreads();
  for (int off = 1; off < 256; off <<= 1) {
    int v = (t >= off) ? buf[t - off] : 0;
    __syncthreads();
    buf[t] += v;
    __syncthreads();
  }
  if (t < nblk) offs[t] = buf[t] - x;   // exclusive
  if (t == nblk) offs[nblk] = buf[nblk - 1];  // grand total
}

__global__ void scanC_kernel(const int* __restrict__ deg, const int* __restrict__ incl,
                             const int* __restrict__ offs, int* __restrict__ rp,
                             int* __restrict__ cur, int n, int nblk) {
  const int i = blockIdx.x * 1024 + threadIdx.x;
  if (i < n) {
    int v = offs[blockIdx.x] + incl[i] - deg[i];
    rp[i] = v;
    cur[i] = v;
  }
  if (i == 0) rp[n] = offs[nblk];
}

__global__ void scatter_kernel(const int* __restrict__ ei, int* __restrict__ cur,
                               int* __restrict__ csr, int E, int tot) {
  int i = blockIdx.x * blockDim.x + threadIdx.x;
  if (i < tot) {
    int src = (i < E) ? ei[i] : (i - E);
    int dst = (i < E) ? ei[E + i] : (i - E);
    int pos = atomicAdd(&cur[dst], 1);
    csr[pos] = src;
  }
}

// ---------------- W transpose + bf16 cast: f32 [K][256] -> bf16 [256][K] ----------------
__global__ void transpose_kernel(const float* __restrict__ W, ushort* __restrict__ Wt, int K) {
  int i = blockIdx.x * blockDim.x + threadIdx.x;
  if (i < K * 256) {
    int k = i >> 8, m = i & 255;
    Wt[m * K + k] = f2bf(W[i]);
  }
}

// ---------------- GEMM (layer 0): hb = A_f32[nrows,512] @ W ----------------
// A split hi/lo bf16 during staging -> near-fp32 precision.
__global__ __launch_bounds__(256) void gemm_kernel(
    const float* __restrict__ A, const ushort* __restrict__ Bt,
    ushort* __restrict__ hb, int nrows, int K) {
  __shared__ ushort At[128 * ASTR];
  __shared__ ushort Bs[128 * BSTR];
  const int tid  = threadIdx.x;
  const int lane = tid & 63;
  const int wave = tid >> 6;
  const int quad = lane >> 4;
  const int m16  = lane & 15;
  const int row0 = blockIdx.x * 128;
  const int col0 = blockIdx.y * 128;
  const int wm = (wave >> 1) * 64;
  const int wn = (wave & 1) * 64;

  floatx4 acc[4][4];
  #pragma unroll
  for (int i = 0; i < 4; i++)
    #pragma unroll
    for (int j = 0; j < 4; j++) acc[i][j] = (floatx4){0.f, 0.f, 0.f, 0.f};

  const int arow = tid >> 3;
  const int acol = (tid & 7) * 4;
  const int brow = tid >> 2;
  const int bcol = (tid & 3) * 8;

  for (int k0 = 0; k0 < K; k0 += 32) {
    #pragma unroll
    for (int i = 0; i < 4; i++) {
      int r = arow + 32 * i;
      int ar = min(row0 + r, nrows - 1);
      floatx4 v = *(const floatx4*)(A + (size_t)ar * K + k0 + acol);
      union { ushort us[4]; unsigned long long u64; } ph, pl;
      #pragma unroll
      for (int j = 0; j < 4; j++) {
        ushort hi = f2bf(v[j]);
        ph.us[j] = hi;
        pl.us[j] = f2bf(v[j] - bf2f(hi));
      }
      *(unsigned long long*)&At[r * ASTR + acol]      = ph.u64;
      *(unsigned long long*)&At[r * ASTR + 32 + acol] = pl.u64;
    }
    #pragma unroll
    for (int i = 0; i < 2; i++) {
      int r = brow + 64 * i;
      *(int4*)&Bs[r * BSTR + bcol] =
          *(const int4*)(Bt + (size_t)(col0 + r) * K + k0 + bcol);
    }
    __syncthreads();
    bf16x8 bfr[4];
    #pragma unroll
    for (int j = 0; j < 4; j++)
      bfr[j] = *(const bf16x8*)&Bs[(wn + j * 16 + m16) * BSTR + quad * 8];
    #pragma unroll
    for (int p = 0; p < 2; p++) {
      bf16x8 af[4];
      #pragma unroll
      for (int i = 0; i < 4; i++)
        af[i] = *(const bf16x8*)&At[(wm + i * 16 + m16) * ASTR + p * 32 + quad * 8];
      #pragma unroll
      for (int i = 0; i < 4; i++)
        #pragma unroll
        for (int j = 0; j < 4; j++)
          acc[i][j] = __builtin_amdgcn_mfma_f32_16x16x32_bf16(af[i], bfr[j], acc[i][j], 0, 0, 0);
    }
    __syncthreads();
  }
  #pragma unroll
  for (int i = 0; i < 4; i++) {
    int rbase = row0 + wm + i * 16 + quad * 4;
    #pragma unroll
    for (int j = 0; j < 4; j++) {
      int col = col0 + wn + j * 16 + m16;
      #pragma unroll
      for (int r = 0; r < 4; r++) {
        int row = rbase + r;
        if (row < nrows) hb[(size_t)row * HID + col] = f2bf(acc[i][j][r]);
      }
    }
  }
}

// ---------------- GEMM (layers 1-2): hb = apk[nrows,512](hi|lo) @ W-replicated ----------------
// Straight K=512 bf16 GEMM; B slice index k0&255 replicates W. Staging = pure copies.
__global__ __launch_bounds__(256) void gemm_packed_kernel(
    const ushort* __restrict__ A, const ushort* __restrict__ Bt,
    ushort* __restrict__ hb, int nrows) {
  __shared__ ushort At[128 * BSTR];
  __shared__ ushort Bs[128 * BSTR];
  const int tid  = threadIdx.x;
  const int lane = tid & 63;
  const int wave = tid >> 6;
  const int quad = lane >> 4;
  const int m16  = lane & 15;
  const int row0 = blockIdx.x * 128;
  const int col0 = blockIdx.y * 128;
  const int wm = (wave >> 1) * 64;
  const int wn = (wave & 1) * 64;

  floatx4 acc[4][4];
  #pragma unroll
  for (int i = 0; i < 4; i++)
    #pragma unroll
    for (int j = 0; j < 4; j++) acc[i][j] = (floatx4){0.f, 0.f, 0.f, 0.f};

  const int srow = tid >> 2;        // 64 rows per pass
  const int scol = (tid & 3) * 8;   // 8 ushorts each

  for (int k0 = 0; k0 < 512; k0 += 32) {
    const int kb = k0 & 255;
    #pragma unroll
    for (int i = 0; i < 2; i++) {
      int r = srow + 64 * i;
      int ar = min(row0 + r, nrows - 1);
      *(int4*)&At[r * BSTR + scol] = *(const int4*)(A + (size_t)ar * 512 + k0 + scol);
      *(int4*)&Bs[r * BSTR + scol] = *(const int4*)(Bt + (size_t)(col0 + r) * 256 + kb + scol);
    }
    __syncthreads();
    bf16x8 af[4], bfr[4];
    #pragma unroll
    for (int j = 0; j < 4; j++)
      bfr[j] = *(const bf16x8*)&Bs[(wn + j * 16 + m16) * BSTR + quad * 8];
    #pragma unroll
    for (int i = 0; i < 4; i++)
      af[i] = *(const bf16x8*)&At[(wm + i * 16 + m16) * BSTR + quad * 8];
    #pragma unroll
    for (int i = 0; i < 4; i++)
      #pragma unroll
      for (int j = 0; j < 4; j++)
        acc[i][j] = __builtin_amdgcn_mfma_f32_16x16x32_bf16(af[i], bfr[j], acc[i][j], 0, 0, 0);
    __syncthreads();
  }
  #pragma unroll
  for (int i = 0; i < 4; i++) {
    int rbase = row0 + wm + i * 16 + quad * 4;
    #pragma unroll
    for (int j = 0; j < 4; j++) {
      int col = col0 + wn + j * 16 + m16;
      #pragma unroll
      for (int r = 0; r < 4; r++) {
        int row = rbase + r;
        if (row < nrows) hb[(size_t)row * HID + col] = f2bf(acc[i][j][r]);
      }
    }
  }
}

// ---------------- per-node alpha_src / alpha_dst dots (bf16 h) ----------------
__global__ __launch_bounds__(256) void alpha_kernel(
    const ushort* __restrict__ hb, const float* __restrict__ avs,
    const float* __restrict__ avd, float* __restrict__ asrc,
    float* __restrict__ adst, int H) {
  const int n = blockIdx.x, t = threadIdx.x;
  float hv = bf2f(hb[(size_t)n * HID + t]);
  float s = hv * avs[t];
  float d = hv * avd[t];
  #pragma unroll
  for (int o = 32; o > 0; o >>= 1) { s += __shfl_xor(s, o); d += __shfl_xor(d, o); }
  __shared__ float ls[4], ld_[4];
  int w = t >> 6;
  if ((t & 63) == 0) { ls[w] = s; ld_[w] = d; }
  __syncthreads();
  if (H == 4) {
    if ((t & 63) == 0) { asrc[n * 4 + w] = ls[w]; adst[n * 4 + w] = ld_[w]; }
  } else {
    if (t == 0) {
      asrc[n] = ls[0] + ls[1] + ls[2] + ls[3];
      adst[n] = ld_[0] + ld_[1] + ld_[2] + ld_[3];
    }
  }
}

// ---- fused segment softmax + aggregation + bias + LayerNorm + ELU ----
// ONE WAVE PER NODE (4 nodes / 256-thread block). Lane covers 4 channels
// (dwordx2 gather -> 512B coalesced row read per edge). Lane's head = lane>>4.
// Phase A: chunk of CH edges (16 if H=4, 64 if H=1); lane (h*CH+j) computes ex
// for (edge j, head h) -> per-wave LDS stash {ex, src<<9}. Phase B: broadcast
// ds_read + packed gather + 4 fmacs. Epilogue barrier-free (wave-local LN).
// Output: apk packed hi|lo bf16 [n,512] (layers 0-1) or f32 out (layer 2).
__global__ __launch_bounds__(256) void agg_ln_kernel(
    const ushort* __restrict__ hb, const float* __restrict__ asrc,
    const float* __restrict__ adst, const int* __restrict__ rp,
    const int* __restrict__ csr,
    const float* __restrict__ bias, const float* __restrict__ lnw,
    const float* __restrict__ lnb, ushort* __restrict__ apk,
    float* __restrict__ fout, int H, int n) {
  __shared__ float2 exs[4][64];
  const int t = threadIdx.x;
  const int w = t >> 6, lane = t & 63;
  const int nid = blockIdx.x * 4 + w;
  if (nid >= n) return;
  const int CH = (H == 4) ? 16 : 64;   // edges per chunk
  const int jj = lane & (CH - 1);
  const int hh = (H == 4) ? (lane >> 4) : 0;   // this lane's head
  const int ch = 4 * lane;                     // first of 4 channels
  const float ad = adst[nid * H + hh];
  const int beg = rp[nid], end = rp[nid + 1];
  const char* hbase = (const char*)hb + ch * 2;
  float den = 0.f, a0 = 0.f, a1 = 0.f, a2 = 0.f, a3 = 0.f;

  for (int c0 = beg; c0 < end; c0 += CH) {
    const int cnt = min(CH, end - c0);
    // phase A
    int s = (lane < cnt) ? csr[c0 + lane] : 0;
    s = __shfl(s, jj);                 // broadcast edge jj's src to all heads
    float ex = 0.f;
    if (jj < cnt) {
      float e = asrc[s * H + hh] + ad;
      e = (e > 0.f) ? e : 0.2f * e;    // leaky_relu 0.2
      ex = __expf(fminf(e, 60.f));
    }
    exs[w][lane] = make_float2(ex, __int_as_float(s << 9));
    float dsum = ex;
    #pragma unroll
    for (int o = 32; o > 0; o >>= 1)
      if (o < CH) dsum += __shfl_xor(dsum, o);   // reduce within head group
    den += dsum;
    // phase B: gather 4 channels per lane per edge
    float2 p = exs[w][hh * CH];
    for (int j = 0; j < cnt; j++) {
      float2 pn = exs[w][hh * CH + ((j + 1 < cnt) ? j + 1 : j)];
      uint2 hv = *(const uint2*)(hbase + __float_as_int(p.y));
      a0 = fmaf(p.x, __uint_as_float(hv.x << 16), a0);
      a1 = fmaf(p.x, __uint_as_float(hv.x & 0xffff0000u), a1);
      a2 = fmaf(p.x, __uint_as_float(hv.y << 16), a2);
      a3 = fmaf(p.x, __uint_as_float(hv.y & 0xffff0000u), a3);
      p = pn;
    }
  }

  // epilogue: bias + LN + ELU on this lane's 4 channels (wave-local, no barriers)
  const float inv = 1.f / den;
  const floatx4 bia = *(const floatx4*)(bias + ch);
  float v0 = a0 * inv + bia[0];
  float v1 = a1 * inv + bia[1];
  float v2 = a2 * inv + bia[2];
  float v3 = a3 * inv + bia[3];
  float r1 = v0 + v1 + v2 + v3;
  #pragma unroll
  for (int o = 32; o > 0; o >>= 1) r1 += __shfl_xor(r1, o);
  float mu = r1 * (1.f / HID);
  float d0 = v0 - mu, d1 = v1 - mu, d2 = v2 - mu, d3 = v3 - mu;
  float r2 = d0 * d0 + d1 * d1 + d2 * d2 + d3 * d3;
  #pragma unroll
  for (int o = 32; o > 0; o >>= 1) r2 += __shfl_xor(r2, o);
  float rstd = rsqrtf(r2 * (1.f / HID) + EPSV);
  const floatx4 wv = *(const floatx4*)(lnw + ch);
  const floatx4 bv = *(const floatx4*)(lnb + ch);
  float y0 = d0 * rstd * wv[0] + bv[0];
  float y1 = d1 * rstd * wv[1] + bv[1];
  float y2 = d2 * rstd * wv[2] + bv[2];
  float y3 = d3 * rstd * wv[3] + bv[3];
  float o0 = (y0 > 0.f) ? y0 : expm1f(y0);   // ELU
  float o1 = (y1 > 0.f) ? y1 : expm1f(y1);
  float o2 = (y2 > 0.f) ? y2 : expm1f(y2);
  float o3 = (y3 > 0.f) ? y3 : expm1f(y3);
  if (apk) {
    union { ushort us[4]; unsigned long long u64; } ph, pl;
    ushort h0 = f2bf(o0), h1 = f2bf(o1), h2 = f2bf(o2), h3 = f2bf(o3);
    ph.us[0] = h0; ph.us[1] = h1; ph.us[2] = h2; ph.us[3] = h3;
    pl.us[0] = f2bf(o0 - bf2f(h0)); pl.us[1] = f2bf(o1 - bf2f(h1));
    pl.us[2] = f2bf(o2 - bf2f(h2)); pl.us[3] = f2bf(o3 - bf2f(h3));
    *(unsigned long long*)(apk + (size_t)nid * 512 + ch)       = ph.u64;
    *(unsigned long long*)(apk + (size_t)nid * 512 + 256 + ch) = pl.u64;
  } else {
    floatx4 ov; ov[0] = o0; ov[1] = o1; ov[2] = o2; ov[3] = o3;
    *(floatx4*)(fout + (size_t)nid * HID + ch) = ov;
  }
}

extern "C" void kernel_launch(void* const* d_in, const int* in_sizes, int n_in,
                              void* d_out, int out_size, void* d_ws, size_t ws_size,
                              hipStream_t stream) {
  const float* x  = (const float*)d_in[0];
  const int*   ei = (const int*)d_in[1];
  const float* Wm[3]  = {(const float*)d_in[2], (const float*)d_in[8],  (const float*)d_in[14]};
  const float* Avs[3] = {(const float*)d_in[3], (const float*)d_in[9],  (const float*)d_in[15]};
  const float* Avd[3] = {(const float*)d_in[4], (const float*)d_in[10], (const float*)d_in[16]};
  const float* Bia[3] = {(const float*)d_in[5], (const float*)d_in[11], (const float*)d_in[17]};
  const float* Lnw[3] = {(const float*)d_in[6], (const float*)d_in[12], (const float*)d_in[18]};
  const float* Lnb[3] = {(const float*)d_in[7], (const float*)d_in[13], (const float*)d_in[19]};
  const int n = in_sizes[0] / 512;   // 50000
  const int E = in_sizes[1] / 2;     // 800000
  const int tot = E + n;             // with self-loops
  const int nblk = (n + 1023) / 1024;

  char* p = (char*)d_ws;
  ushort* hb   = (ushort*)p; p += (size_t)n * HID * 2;   // 25.6 MB (bf16 h)
  ushort* apk  = (ushort*)p; p += (size_t)n * 512 * 2;   // 51.2 MB (packed hi|lo act)
  ushort* Wt   = (ushort*)p; p += 256 * 512 * 2;
  float*  asrc = (float*)p;  p += (size_t)n * 4 * 4;
  float*  adst = (float*)p;  p += (size_t)n * 4 * 4;
  int* rp   = (int*)p; p += (size_t)(n + 1) * 4;
  int* cur  = (int*)p; p += (size_t)n * 4;
  int* csr  = (int*)p; p += (size_t)tot * 4;
  int* deg  = (int*)p; p += (size_t)n * 4;
  int* incl = (int*)p; p += (size_t)n * 4;
  int* sums = (int*)p; p += (size_t)(nblk + 1) * 4;
  int* offs = (int*)p; p += (size_t)(nblk + 1) * 4;

  // --- CSR by destination (graph identical for all 3 layers) ---
  hipMemsetAsync(deg, 0, (size_t)n * 4, stream);
  count_kernel<<<(tot + 255) / 256, 256, 0, stream>>>(ei, deg, E, tot);
  scanA_kernel<<<nblk, 1024, 0, stream>>>(deg, incl, sums, n);
  scanB_kernel<<<1, 256, 0, stream>>>(sums, offs, nblk);
  scanC_kernel<<<nblk, 1024, 0, stream>>>(deg, incl, offs, rp, cur, n, nblk);
  scatter_kernel<<<(tot + 255) / 256, 256, 0, stream>>>(ei, cur, csr, E, tot);

  const int KB[3] = {512, 256, 256};
  const int HH[3] = {4, 4, 1};
  dim3 gg((n + 127) / 128, 2);
  for (int l = 0; l < 3; l++) {
    transpose_kernel<<<(KB[l] * 256 + 255) / 256, 256, 0, stream>>>(Wm[l], Wt, KB[l]);
    if (l == 0)
      gemm_kernel<<<gg, 256, 0, stream>>>(x, Wt, hb, n, 512);
    else
      gemm_packed_kernel<<<gg, 256, 0, stream>>>(apk, Wt, hb, n);
    alpha_kernel<<<n, 256, 0, stream>>>(hb, Avs[l], Avd[l], asrc, adst, HH[l]);
    agg_ln_kernel<<<(n + 3) / 4, 256, 0, stream>>>(
        hb, asrc, adst, rp, csr, Bia[l], Lnw[l], Lnb[l],
        (l < 2) ? apk : (ushort*)nullptr,
        (l == 2) ? (float*)d_out : (float*)nullptr, HH[l], n);
  }
}

// Round 7
// 642.293 us; speedup vs baseline: 1.1337x; 1.1337x over previous
//
#include <hip/hip_runtime.h>

#define HID 256
#define EPSV 1e-5f
#define ASTR 72   // layer-0 At row stride (ushorts): 64 data + 8 pad
#define BSTR 40   // 32 data + 8 pad

typedef __bf16 bf16x8 __attribute__((ext_vector_type(8)));
typedef float  floatx4 __attribute__((ext_vector_type(4)));

static __device__ __forceinline__ ushort f2bf(float f) {
  union { float f; unsigned int i; } c; c.f = f;
  unsigned int u = c.i;
  u += 0x7FFFu + ((u >> 16) & 1u);   // round-to-nearest-even
  return (ushort)(u >> 16);
}
static __device__ __forceinline__ float bf2f(ushort u) {
  union { unsigned int i; float f; } c; c.i = ((unsigned int)u) << 16; return c.f;
}

// ---------------- CSR build ----------------
__global__ void count_kernel(const int* __restrict__ ei, int* __restrict__ deg, int E, int tot) {
  int i = blockIdx.x * blockDim.x + threadIdx.x;
  if (i < tot) {
    int dst = (i < E) ? ei[E + i] : (i - E);
    atomicAdd(&deg[dst], 1);
  }
}

// hierarchical exclusive scan of deg -> rp
__global__ void scanA_kernel(const int* __restrict__ deg, int* __restrict__ incl,
                             int* __restrict__ sums, int n) {
  __shared__ int buf[1024];
  const int t = threadIdx.x;
  const int i = blockIdx.x * 1024 + t;
  int x = (i < n) ? deg[i] : 0;
  buf[t] = x;
  __syncthreads();
  for (int off = 1; off < 1024; off <<= 1) {
    int v = (t >= off) ? buf[t - off] : 0;
    __syncthreads();
    buf[t] += v;
    __syncthreads();
  }
  if (i < n) incl[i] = buf[t];
  if (t == 1023) sums[blockIdx.x] = buf[1023];
}

__global__ void scanB_kernel(int* __restrict__ sums, int* __restrict__ offs, int nblk) {
  __shared__ int buf[256];
  const int t = threadIdx.x;
  int x = (t < nblk) ? sums[t] : 0;
  buf[t] = x;
  __syncthreads();
  for (int off = 1; off < 256; off <<= 1) {
    int v = (t >= off) ? buf[t - off] : 0;
    __syncthreads();
    buf[t] += v;
    __syncthreads();
  }
  if (t < nblk) offs[t] = buf[t] - x;   // exclusive
  if (t == nblk) offs[nblk] = buf[nblk - 1];  // grand total
}

__global__ void scanC_kernel(const int* __restrict__ deg, const int* __restrict__ incl,
                             const int* __restrict__ offs, int* __restrict__ rp,
                             int* __restrict__ cur, int n, int nblk) {
  const int i = blockIdx.x * 1024 + threadIdx.x;
  if (i < n) {
    int v = offs[blockIdx.x] + incl[i] - deg[i];
    rp[i] = v;
    cur[i] = v;
  }
  if (i == 0) rp[n] = offs[nblk];
}

__global__ void scatter_kernel(const int* __restrict__ ei, int* __restrict__ cur,
                               int* __restrict__ csr, int E, int tot) {
  int i = blockIdx.x * blockDim.x + threadIdx.x;
  if (i < tot) {
    int src = (i < E) ? ei[i] : (i - E);
    int dst = (i < E) ? ei[E + i] : (i - E);
    int pos = atomicAdd(&cur[dst], 1);
    csr[pos] = src;
  }
}

// ---------------- W transpose + bf16 cast: f32 [K][256] -> bf16 [256][K] ----------------
__global__ void transpose_kernel(const float* __restrict__ W, ushort* __restrict__ Wt, int K) {
  int i = blockIdx.x * blockDim.x + threadIdx.x;
  if (i < K * 256) {
    int k = i >> 8, m = i & 255;
    Wt[m * K + k] = f2bf(W[i]);
  }
}

// ---------------- GEMM (layer 0): hb = A_f32[nrows,512] @ W ----------------
__global__ __launch_bounds__(256) void gemm_kernel(
    const float* __restrict__ A, const ushort* __restrict__ Bt,
    ushort* __restrict__ hb, int nrows, int K) {
  __shared__ ushort At[128 * ASTR];
  __shared__ ushort Bs[128 * BSTR];
  const int tid  = threadIdx.x;
  const int lane = tid & 63;
  const int wave = tid >> 6;
  const int quad = lane >> 4;
  const int m16  = lane & 15;
  const int row0 = blockIdx.x * 128;
  const int col0 = blockIdx.y * 128;
  const int wm = (wave >> 1) * 64;
  const int wn = (wave & 1) * 64;

  floatx4 acc[4][4];
  #pragma unroll
  for (int i = 0; i < 4; i++)
    #pragma unroll
    for (int j = 0; j < 4; j++) acc[i][j] = (floatx4){0.f, 0.f, 0.f, 0.f};

  const int arow = tid >> 3;
  const int acol = (tid & 7) * 4;
  const int brow = tid >> 2;
  const int bcol = (tid & 3) * 8;

  for (int k0 = 0; k0 < K; k0 += 32) {
    #pragma unroll
    for (int i = 0; i < 4; i++) {
      int r = arow + 32 * i;
      int ar = min(row0 + r, nrows - 1);
      floatx4 v = *(const floatx4*)(A + (size_t)ar * K + k0 + acol);
      union { ushort us[4]; unsigned long long u64; } ph, pl;
      #pragma unroll
      for (int j = 0; j < 4; j++) {
        ushort hi = f2bf(v[j]);
        ph.us[j] = hi;
        pl.us[j] = f2bf(v[j] - bf2f(hi));
      }
      *(unsigned long long*)&At[r * ASTR + acol]      = ph.u64;
      *(unsigned long long*)&At[r * ASTR + 32 + acol] = pl.u64;
    }
    #pragma unroll
    for (int i = 0; i < 2; i++) {
      int r = brow + 64 * i;
      *(int4*)&Bs[r * BSTR + bcol] =
          *(const int4*)(Bt + (size_t)(col0 + r) * K + k0 + bcol);
    }
    __syncthreads();
    bf16x8 bfr[4];
    #pragma unroll
    for (int j = 0; j < 4; j++)
      bfr[j] = *(const bf16x8*)&Bs[(wn + j * 16 + m16) * BSTR + quad * 8];
    #pragma unroll
    for (int p = 0; p < 2; p++) {
      bf16x8 af[4];
      #pragma unroll
      for (int i = 0; i < 4; i++)
        af[i] = *(const bf16x8*)&At[(wm + i * 16 + m16) * ASTR + p * 32 + quad * 8];
      #pragma unroll
      for (int i = 0; i < 4; i++)
        #pragma unroll
        for (int j = 0; j < 4; j++)
          acc[i][j] = __builtin_amdgcn_mfma_f32_16x16x32_bf16(af[i], bfr[j], acc[i][j], 0, 0, 0);
    }
    __syncthreads();
  }
  #pragma unroll
  for (int i = 0; i < 4; i++) {
    int rbase = row0 + wm + i * 16 + quad * 4;
    #pragma unroll
    for (int j = 0; j < 4; j++) {
      int col = col0 + wn + j * 16 + m16;
      #pragma unroll
      for (int r = 0; r < 4; r++) {
        int row = rbase + r;
        if (row < nrows) hb[(size_t)row * HID + col] = f2bf(acc[i][j][r]);
      }
    }
  }
}

// ---------------- GEMM (layers 1-2): hb = apk[nrows,512](hi|lo) @ W-replicated ----------------
__global__ __launch_bounds__(256) void gemm_packed_kernel(
    const ushort* __restrict__ A, const ushort* __restrict__ Bt,
    ushort* __restrict__ hb, int nrows) {
  __shared__ ushort At[128 * BSTR];
  __shared__ ushort Bs[128 * BSTR];
  const int tid  = threadIdx.x;
  const int lane = tid & 63;
  const int wave = tid >> 6;
  const int quad = lane >> 4;
  const int m16  = lane & 15;
  const int row0 = blockIdx.x * 128;
  const int col0 = blockIdx.y * 128;
  const int wm = (wave >> 1) * 64;
  const int wn = (wave & 1) * 64;

  floatx4 acc[4][4];
  #pragma unroll
  for (int i = 0; i < 4; i++)
    #pragma unroll
    for (int j = 0; j < 4; j++) acc[i][j] = (floatx4){0.f, 0.f, 0.f, 0.f};

  const int srow = tid >> 2;
  const int scol = (tid & 3) * 8;

  for (int k0 = 0; k0 < 512; k0 += 32) {
    const int kb = k0 & 255;
    #pragma unroll
    for (int i = 0; i < 2; i++) {
      int r = srow + 64 * i;
      int ar = min(row0 + r, nrows - 1);
      *(int4*)&At[r * BSTR + scol] = *(const int4*)(A + (size_t)ar * 512 + k0 + scol);
      *(int4*)&Bs[r * BSTR + scol] = *(const int4*)(Bt + (size_t)(col0 + r) * 256 + kb + scol);
    }
    __syncthreads();
    bf16x8 af[4], bfr[4];
    #pragma unroll
    for (int j = 0; j < 4; j++)
      bfr[j] = *(const bf16x8*)&Bs[(wn + j * 16 + m16) * BSTR + quad * 8];
    #pragma unroll
    for (int i = 0; i < 4; i++)
      af[i] = *(const bf16x8*)&At[(wm + i * 16 + m16) * BSTR + quad * 8];
    #pragma unroll
    for (int i = 0; i < 4; i++)
      #pragma unroll
      for (int j = 0; j < 4; j++)
        acc[i][j] = __builtin_amdgcn_mfma_f32_16x16x32_bf16(af[i], bfr[j], acc[i][j], 0, 0, 0);
    __syncthreads();
  }
  #pragma unroll
  for (int i = 0; i < 4; i++) {
    int rbase = row0 + wm + i * 16 + quad * 4;
    #pragma unroll
    for (int j = 0; j < 4; j++) {
      int col = col0 + wn + j * 16 + m16;
      #pragma unroll
      for (int r = 0; r < 4; r++) {
        int row = rbase + r;
        if (row < nrows) hb[(size_t)row * HID + col] = f2bf(acc[i][j][r]);
      }
    }
  }
}

// ---------------- per-node alpha dots: 1 wave/node, 4 ch/lane ----------------
__global__ __launch_bounds__(256) void alpha_kernel(
    const ushort* __restrict__ hb, const float* __restrict__ avs,
    const float* __restrict__ avd, float* __restrict__ asrc,
    float* __restrict__ adst, int H, int n) {
  const int t = threadIdx.x, w = t >> 6, lane = t & 63;
  const int nid = blockIdx.x * 4 + w;
  if (nid >= n) return;
  const int ch = 4 * lane;
  uint2 hv = *(const uint2*)(hb + (size_t)nid * HID + ch);
  float h0 = __uint_as_float(hv.x << 16);
  float h1 = __uint_as_float(hv.x & 0xffff0000u);
  float h2 = __uint_as_float(hv.y << 16);
  float h3 = __uint_as_float(hv.y & 0xffff0000u);
  floatx4 vs = *(const floatx4*)(avs + ch);
  floatx4 vd = *(const floatx4*)(avd + ch);
  float s = h0 * vs[0] + h1 * vs[1] + h2 * vs[2] + h3 * vs[3];
  float d = h0 * vd[0] + h1 * vd[1] + h2 * vd[2] + h3 * vd[3];
  #pragma unroll
  for (int o = 1; o < 16; o <<= 1) { s += __shfl_xor(s, o); d += __shfl_xor(d, o); }
  if (H == 4) {
    if ((lane & 15) == 0) {
      int hh = lane >> 4;
      asrc[nid * 4 + hh] = s;
      adst[nid * 4 + hh] = d;
    }
  } else {
    s += __shfl_xor(s, 16); d += __shfl_xor(d, 16);
    s += __shfl_xor(s, 32); d += __shfl_xor(d, 32);
    if (lane == 0) { asrc[nid] = s; adst[nid] = d; }
  }
}

// ---- fused segment softmax + aggregation + bias + LayerNorm + ELU ----
// ONE WAVE PER NODE, 4 ch/lane. Phase B unrolled x2 with dual accumulators:
// two independent dwordx2 gathers in flight per iteration (latency hiding via
// ILP — round-6 lesson: single outstanding load/wave was the bottleneck).
__global__ __launch_bounds__(256) void agg_ln_kernel(
    const ushort* __restrict__ hb, const float* __restrict__ asrc,
    const float* __restrict__ adst, const int* __restrict__ rp,
    const int* __restrict__ csr,
    const float* __restrict__ bias, const float* __restrict__ lnw,
    const float* __restrict__ lnb, ushort* __restrict__ apk,
    float* __restrict__ fout, int H, int n) {
  __shared__ float2 exs[4][64];
  const int t = threadIdx.x;
  const int w = t >> 6, lane = t & 63;
  const int nid = blockIdx.x * 4 + w;
  if (nid >= n) return;
  const int CH = (H == 4) ? 16 : 64;   // edges per chunk
  const int jj = lane & (CH - 1);
  const int hh = (H == 4) ? (lane >> 4) : 0;
  const int ch = 4 * lane;
  const float ad = adst[nid * H + hh];
  const int beg = rp[nid], end = rp[nid + 1];
  const char* hbase = (const char*)hb + ch * 2;
  float den = 0.f;
  float a0 = 0.f, a1 = 0.f, a2 = 0.f, a3 = 0.f;
  float b0 = 0.f, b1 = 0.f, b2 = 0.f, b3 = 0.f;

  for (int c0 = beg; c0 < end; c0 += CH) {
    const int cnt = min(CH, end - c0);
    // phase A
    int s = (lane < cnt) ? csr[c0 + lane] : 0;
    s = __shfl(s, jj);
    float ex = 0.f;
    if (jj < cnt) {
      float e = asrc[s * H + hh] + ad;
      e = (e > 0.f) ? e : 0.2f * e;    // leaky_relu 0.2
      ex = __expf(fminf(e, 60.f));
    }
    exs[w][lane] = make_float2(ex, __int_as_float(s << 9));
    float dsum = ex;
    #pragma unroll
    for (int o = 32; o > 0; o >>= 1)
      if (o < CH) dsum += __shfl_xor(dsum, o);
    den += dsum;
    // phase B: unroll x2, dual accumulators, 2 loads in flight
    const float2* exw = &exs[w][hh * CH];
    int j = 0;
    for (; j + 2 <= cnt; j += 2) {
      float2 q0 = exw[j];
      float2 q1 = exw[j + 1];
      uint2 u0 = *(const uint2*)(hbase + __float_as_int(q0.y));
      uint2 u1 = *(const uint2*)(hbase + __float_as_int(q1.y));
      a0 = fmaf(q0.x, __uint_as_float(u0.x << 16), a0);
      a1 = fmaf(q0.x, __uint_as_float(u0.x & 0xffff0000u), a1);
      a2 = fmaf(q0.x, __uint_as_float(u0.y << 16), a2);
      a3 = fmaf(q0.x, __uint_as_float(u0.y & 0xffff0000u), a3);
      b0 = fmaf(q1.x, __uint_as_float(u1.x << 16), b0);
      b1 = fmaf(q1.x, __uint_as_float(u1.x & 0xffff0000u), b1);
      b2 = fmaf(q1.x, __uint_as_float(u1.y << 16), b2);
      b3 = fmaf(q1.x, __uint_as_float(u1.y & 0xffff0000u), b3);
    }
    if (j < cnt) {
      float2 q0 = exw[j];
      uint2 u0 = *(const uint2*)(hbase + __float_as_int(q0.y));
      a0 = fmaf(q0.x, __uint_as_float(u0.x << 16), a0);
      a1 = fmaf(q0.x, __uint_as_float(u0.x & 0xffff0000u), a1);
      a2 = fmaf(q0.x, __uint_as_float(u0.y << 16), a2);
      a3 = fmaf(q0.x, __uint_as_float(u0.y & 0xffff0000u), a3);
    }
  }
  a0 += b0; a1 += b1; a2 += b2; a3 += b3;

  // epilogue: bias + LN + ELU (wave-local, barrier-free)
  const float inv = 1.f / den;
  const floatx4 bia = *(const floatx4*)(bias + ch);
  float v0 = a0 * inv + bia[0];
  float v1 = a1 * inv + bia[1];
  float v2 = a2 * inv + bia[2];
  float v3 = a3 * inv + bia[3];
  float r1 = v0 + v1 + v2 + v3;
  #pragma unroll
  for (int o = 32; o > 0; o >>= 1) r1 += __shfl_xor(r1, o);
  float mu = r1 * (1.f / HID);
  float d0 = v0 - mu, d1 = v1 - mu, d2 = v2 - mu, d3 = v3 - mu;
  float r2 = d0 * d0 + d1 * d1 + d2 * d2 + d3 * d3;
  #pragma unroll
  for (int o = 32; o > 0; o >>= 1) r2 += __shfl_xor(r2, o);
  float rstd = rsqrtf(r2 * (1.f / HID) + EPSV);
  const floatx4 wv = *(const floatx4*)(lnw + ch);
  const floatx4 bv = *(const floatx4*)(lnb + ch);
  float y0 = d0 * rstd * wv[0] + bv[0];
  float y1 = d1 * rstd * wv[1] + bv[1];
  float y2 = d2 * rstd * wv[2] + bv[2];
  float y3 = d3 * rstd * wv[3] + bv[3];
  float o0 = (y0 > 0.f) ? y0 : expm1f(y0);   // ELU
  float o1 = (y1 > 0.f) ? y1 : expm1f(y1);
  float o2 = (y2 > 0.f) ? y2 : expm1f(y2);
  float o3 = (y3 > 0.f) ? y3 : expm1f(y3);
  if (apk) {
    union { ushort us[4]; unsigned long long u64; } ph, pl;
    ushort h0 = f2bf(o0), h1 = f2bf(o1), h2 = f2bf(o2), h3 = f2bf(o3);
    ph.us[0] = h0; ph.us[1] = h1; ph.us[2] = h2; ph.us[3] = h3;
    pl.us[0] = f2bf(o0 - bf2f(h0)); pl.us[1] = f2bf(o1 - bf2f(h1));
    pl.us[2] = f2bf(o2 - bf2f(h2)); pl.us[3] = f2bf(o3 - bf2f(h3));
    *(unsigned long long*)(apk + (size_t)nid * 512 + ch)       = ph.u64;
    *(unsigned long long*)(apk + (size_t)nid * 512 + 256 + ch) = pl.u64;
  } else {
    floatx4 ov; ov[0] = o0; ov[1] = o1; ov[2] = o2; ov[3] = o3;
    *(floatx4*)(fout + (size_t)nid * HID + ch) = ov;
  }
}

extern "C" void kernel_launch(void* const* d_in, const int* in_sizes, int n_in,
                              void* d_out, int out_size, void* d_ws, size_t ws_size,
                              hipStream_t stream) {
  const float* x  = (const float*)d_in[0];
  const int*   ei = (const int*)d_in[1];
  const float* Wm[3]  = {(const float*)d_in[2], (const float*)d_in[8],  (const float*)d_in[14]};
  const float* Avs[3] = {(const float*)d_in[3], (const float*)d_in[9],  (const float*)d_in[15]};
  const float* Avd[3] = {(const float*)d_in[4], (const float*)d_in[10], (const float*)d_in[16]};
  const float* Bia[3] = {(const float*)d_in[5], (const float*)d_in[11], (const float*)d_in[17]};
  const float* Lnw[3] = {(const float*)d_in[6], (const float*)d_in[12], (const float*)d_in[18]};
  const float* Lnb[3] = {(const float*)d_in[7], (const float*)d_in[13], (const float*)d_in[19]};
  const int n = in_sizes[0] / 512;   // 50000
  const int E = in_sizes[1] / 2;     // 800000
  const int tot = E + n;             // with self-loops
  const int nblk = (n + 1023) / 1024;

  char* p = (char*)d_ws;
  ushort* hb   = (ushort*)p; p += (size_t)n * HID * 2;   // 25.6 MB (bf16 h)
  ushort* apk  = (ushort*)p; p += (size_t)n * 512 * 2;   // 51.2 MB (packed hi|lo act)
  ushort* Wt   = (ushort*)p; p += 256 * 512 * 2;
  float*  asrc = (float*)p;  p += (size_t)n * 4 * 4;
  float*  adst = (float*)p;  p += (size_t)n * 4 * 4;
  int* rp   = (int*)p; p += (size_t)(n + 1) * 4;
  int* cur  = (int*)p; p += (size_t)n * 4;
  int* csr  = (int*)p; p += (size_t)tot * 4;
  int* deg  = (int*)p; p += (size_t)n * 4;
  int* incl = (int*)p; p += (size_t)n * 4;
  int* sums = (int*)p; p += (size_t)(nblk + 1) * 4;
  int* offs = (int*)p; p += (size_t)(nblk + 1) * 4;

  // --- CSR by destination (graph identical for all 3 layers) ---
  hipMemsetAsync(deg, 0, (size_t)n * 4, stream);
  count_kernel<<<(tot + 255) / 256, 256, 0, stream>>>(ei, deg, E, tot);
  scanA_kernel<<<nblk, 1024, 0, stream>>>(deg, incl, sums, n);
  scanB_kernel<<<1, 256, 0, stream>>>(sums, offs, nblk);
  scanC_kernel<<<nblk, 1024, 0, stream>>>(deg, incl, offs, rp, cur, n, nblk);
  scatter_kernel<<<(tot + 255) / 256, 256, 0, stream>>>(ei, cur, csr, E, tot);

  const int KB[3] = {512, 256, 256};
  const int HH[3] = {4, 4, 1};
  dim3 gg((n + 127) / 128, 2);
  for (int l = 0; l < 3; l++) {
    transpose_kernel<<<(KB[l] * 256 + 255) / 256, 256, 0, stream>>>(Wm[l], Wt, KB[l]);
    if (l == 0)
      gemm_kernel<<<gg, 256, 0, stream>>>(x, Wt, hb, n, 512);
    else
      gemm_packed_kernel<<<gg, 256, 0, stream>>>(apk, Wt, hb, n);
    alpha_kernel<<<(n + 3) / 4, 256, 0, stream>>>(hb, Avs[l], Avd[l], asrc, adst, HH[l], n);
    agg_ln_kernel<<<(n + 3) / 4, 256, 0, stream>>>(
        hb, asrc, adst, rp, csr, Bia[l], Lnw[l], Lnb[l],
        (l < 2) ? apk : (ushort*)nullptr,
        (l == 2) ? (float*)d_out : (float*)nullptr, HH[l], n);
  }
}